// Round 5
// baseline (4611.766 us; speedup 1.0000x reference)
//
#include <hip/hip_runtime.h>

// Problem constants (match reference setup_inputs()).
constexpr int NN   = 100000;  // nodes
constexpr int EE   = 400000;  // directed edges
constexpr int GG   = 4096;    // graphs
constexpr int EMB  = 300;     // node feature dim (75 float4)
constexpr int FEAT = 256;
constexpr int LL   = 5;
constexpr int EMB4 = EMB / 4;   // 75
constexpr float EPSV = 1e-5f;

// ---------------------------------------------------------------- CSR build
__global__ void k_deg(const int* __restrict__ col, int* __restrict__ deg) {
    int e = blockIdx.x * 256 + threadIdx.x;
    if (e < EE) atomicAdd(&deg[col[e]], 1);
}

__global__ void k_alloc(const int* __restrict__ deg, int* __restrict__ start,
                        int* __restrict__ gcur) {
    int c = blockIdx.x * 256 + threadIdx.x;
    if (c < NN) start[c] = atomicAdd(gcur, deg[c]);
}

__global__ void k_fill(const int* __restrict__ row, const int* __restrict__ col,
                       const int* __restrict__ start, int* __restrict__ cur,
                       int* __restrict__ csr) {
    int e = blockIdx.x * 256 + threadIdx.x;
    if (e >= EE) return;
    int c = col[e];
    int p = start[c] + atomicAdd(&cur[c], 1);
    csr[p] = row[e];
}

// ------------------------------------------------- per-node edge-embedding sum
// deg_emb[l][c] = sum over incoming edges of (ee1[l][t0] + ee2[l][t1]);
// self-loop contributes ee1[l][4] + ee2[l][0] (the init term).
__global__ void k_degemb_init(const float* __restrict__ ee1, const float* __restrict__ ee2,
                              float* __restrict__ de) {
    int idx = blockIdx.x * 256 + threadIdx.x;
    if (idx >= LL * NN) return;
    int l = idx / NN;
    de[idx] = ee1[l * 5 + 4] + ee2[l * 3 + 0];
}

__global__ void k_degemb_edges(const int* __restrict__ col, const int* __restrict__ ea,
                               const float* __restrict__ ee1, const float* __restrict__ ee2,
                               float* __restrict__ de) {
    int e = blockIdx.x * 256 + threadIdx.x;
    if (e >= EE) return;
    int c  = col[e];
    int t0 = ea[e * 2 + 0];
    int t1 = ea[e * 2 + 1];
#pragma unroll
    for (int l = 0; l < LL; ++l)
        atomicAdd(&de[l * NN + c], ee1[l * 5 + t0] + ee2[l * 3 + t1]);
}

// ---------------------------------------------------------------- node embed
__global__ void k_embed(const int* __restrict__ xn, const float* __restrict__ e1,
                        const float* __restrict__ e2, float* __restrict__ h) {
    int idx = blockIdx.x * 256 + threadIdx.x;
    if (idx >= NN * EMB4) return;
    int node = idx / EMB4;
    int c    = idx % EMB4;
    int a0 = xn[node * 2 + 0];
    int a1 = xn[node * 2 + 1];
    const float4* e1_4 = (const float4*)e1;
    const float4* e2_4 = (const float4*)e2;
    float4 u = e1_4[(size_t)a0 * EMB4 + c];
    float4 v = e2_4[(size_t)a1 * EMB4 + c];
    ((float4*)h)[idx] = make_float4(u.x + v.x, u.y + v.y, u.z + v.z, u.w + v.w);
}

// ---------------------------------------------------------------- aggregation
// out[node] = h[node] (self loop) + sum over CSR-neighbors h[src]
__global__ void k_agg(const float* __restrict__ h, float* __restrict__ out,
                      const int* __restrict__ csr, const int* __restrict__ start,
                      const int* __restrict__ deg) {
    int idx = blockIdx.x * 256 + threadIdx.x;
    if (idx >= NN * EMB4) return;
    int node = idx / EMB4;
    int c    = idx % EMB4;
    const float4* h4 = (const float4*)h;
    float4 a = h4[(size_t)node * EMB4 + c];
    int s = start[node];
    int d = deg[node];
    for (int i = 0; i < d; ++i) {
        float4 v = h4[(size_t)csr[s + i] * EMB4 + c];
        a.x += v.x; a.y += v.y; a.z += v.z; a.w += v.w;
    }
    ((float4*)out)[idx] = a;
}

// ---------------------------------------------------------------- fp32 GEMM
// C[M,N] = A[M,K] @ B[K,N] (+ row_add[r]) (+ col_bias[c])
// 128x64 tile, BK=16, 256 threads, 8x4 micro-tile.
#define GBM 128
#define GBN 64
#define GBK 16
__global__ __launch_bounds__(256) void k_gemm(
    const float* __restrict__ A, const float* __restrict__ B, float* __restrict__ C,
    int M, int N, int K,
    const float* __restrict__ row_add, const float* __restrict__ col_bias) {
    __shared__ float As[GBK][GBM + 4];
    __shared__ float Bs[GBK][GBN + 4];
    const int t  = threadIdx.x;
    const int tx = t & 15;   // N micro (x4)
    const int ty = t >> 4;   // M micro (x8)
    const int bm0 = blockIdx.x * GBM;
    const int bn0 = blockIdx.y * GBN;

    float acc[8][4];
#pragma unroll
    for (int i = 0; i < 8; ++i)
#pragma unroll
        for (int j = 0; j < 4; ++j) acc[i][j] = 0.f;

    for (int k0 = 0; k0 < K; k0 += GBK) {
        // A tile: 128x16 = 2048 elems, 8 per thread
#pragma unroll
        for (int i = 0; i < 8; ++i) {
            int id = t + i * 256;
            int kk = id & 15, m = id >> 4;
            int r = bm0 + m, k = k0 + kk;
            As[kk][m] = (r < M && k < K) ? A[(size_t)r * K + k] : 0.f;
        }
        // B tile: 16x64 = 1024 elems, 4 per thread
#pragma unroll
        for (int i = 0; i < 4; ++i) {
            int id = t + i * 256;
            int n = id & 63, kk = id >> 6;
            int k = k0 + kk, c = bn0 + n;
            Bs[kk][n] = (k < K && c < N) ? B[(size_t)k * N + c] : 0.f;
        }
        __syncthreads();
#pragma unroll
        for (int kk = 0; kk < GBK; ++kk) {
            float4 a0 = *(const float4*)&As[kk][ty * 8];
            float4 a1 = *(const float4*)&As[kk][ty * 8 + 4];
            float4 b  = *(const float4*)&Bs[kk][tx * 4];
            float av[8] = {a0.x, a0.y, a0.z, a0.w, a1.x, a1.y, a1.z, a1.w};
            float bv[4] = {b.x, b.y, b.z, b.w};
#pragma unroll
            for (int i = 0; i < 8; ++i)
#pragma unroll
                for (int j = 0; j < 4; ++j) acc[i][j] += av[i] * bv[j];
        }
        __syncthreads();
    }
#pragma unroll
    for (int i = 0; i < 8; ++i) {
        int r = bm0 + ty * 8 + i;
        if (r >= M) continue;
        float ra = row_add ? row_add[r] : 0.f;
#pragma unroll
        for (int j = 0; j < 4; ++j) {
            int c = bn0 + tx * 4 + j;
            if (c >= N) continue;
            float v = acc[i][j] + ra;
            if (col_bias) v += col_bias[c];
            C[(size_t)r * N + c] = v;
        }
    }
}

// ---------------------------------------------------------------- BatchNorm
// sums[0..fdim) = sum, sums[fdim..2*fdim) = sum of squares  (pre-zeroed)
__global__ void k_bn_stats(const float* __restrict__ x, int nrows, int fdim,
                           float* __restrict__ sums) {
    int t = threadIdx.x;  // 256
    int rows_per = (nrows + gridDim.x - 1) / gridDim.x;
    int r0 = blockIdx.x * rows_per;
    int r1 = min(nrows, r0 + rows_per);
    bool has2 = (t + 256) < fdim;
    float s0 = 0.f, q0 = 0.f, s1 = 0.f, q1 = 0.f;
    for (int r = r0; r < r1; ++r) {
        const float* row = x + (size_t)r * fdim;
        float v = row[t];
        s0 += v; q0 += v * v;
        if (has2) { float w = row[t + 256]; s1 += w; q1 += w * w; }
    }
    atomicAdd(&sums[t], s0);
    atomicAdd(&sums[fdim + t], q0);
    if (has2) {
        atomicAdd(&sums[t + 256], s1);
        atomicAdd(&sums[fdim + t + 256], q1);
    }
}

// ss[0..fdim) = scale, ss[fdim..2*fdim) = shift
__global__ void k_bn_finalize(const float* __restrict__ sums, const float* __restrict__ gamma,
                              const float* __restrict__ beta, float inv_n, int fdim,
                              float* __restrict__ ss) {
    int f = blockIdx.x * 256 + threadIdx.x;
    if (f >= fdim) return;
    float mean = sums[f] * inv_n;
    float var  = sums[fdim + f] * inv_n - mean * mean;
    float sc   = gamma[f] * rsqrtf(var + EPSV);
    ss[f] = sc;
    ss[fdim + f] = beta[f] - mean * sc;
}

__global__ void k_bn_apply(float* __restrict__ x, long total4, int f4dim,
                           const float* __restrict__ ss, int fdim, int relu) {
    long idx = (long)blockIdx.x * 256 + threadIdx.x;
    if (idx >= total4) return;
    int c4 = (int)(idx % f4dim);
    float4 v = ((float4*)x)[idx];
    float4 sc = *(const float4*)&ss[c4 * 4];
    float4 sh = *(const float4*)&ss[fdim + c4 * 4];
    v.x = v.x * sc.x + sh.x;
    v.y = v.y * sc.y + sh.y;
    v.z = v.z * sc.z + sh.z;
    v.w = v.w * sc.w + sh.w;
    if (relu) {
        v.x = fmaxf(v.x, 0.f); v.y = fmaxf(v.y, 0.f);
        v.z = fmaxf(v.z, 0.f); v.w = fmaxf(v.w, 0.f);
    }
    ((float4*)x)[idx] = v;
}

// ---------------------------------------------------------------- mean pool
// batch is sorted; block g binary-searches its row range.
__global__ void k_pool(const float* __restrict__ h, const int* __restrict__ batch,
                       float* __restrict__ out) {
    int g = blockIdx.x;
    int t = threadIdx.x;  // 256
    int lo = 0, hi = NN;
    while (lo < hi) { int m = (lo + hi) >> 1; if (batch[m] < g) lo = m + 1; else hi = m; }
    int s = lo;
    int g1 = g + 1;
    lo = 0; hi = NN;
    while (lo < hi) { int m = (lo + hi) >> 1; if (batch[m] < g1) lo = m + 1; else hi = m; }
    int e = lo;
    float a0 = 0.f, a1 = 0.f;
    for (int r = s; r < e; ++r) {
        const float* row = h + (size_t)r * EMB;
        a0 += row[t];
        if (t < EMB - 256) a1 += row[t + 256];
    }
    float inv = 1.0f / (float)max(e - s, 1);
    out[(size_t)g * EMB + t] = a0 * inv;
    if (t < EMB - 256) out[(size_t)g * EMB + t + 256] = a1 * inv;
}

// ---------------------------------------------------------------- launcher
extern "C" void kernel_launch(void* const* d_in, const int* in_sizes, int n_in,
                              void* d_out, int out_size, void* d_ws, size_t ws_size,
                              hipStream_t stream) {
    const int*   x_nodes    = (const int*)d_in[0];
    const int*   edge_index = (const int*)d_in[1];
    const int*   edge_attr  = (const int*)d_in[2];
    const int*   batch      = (const int*)d_in[3];
    const float* x_emb1     = (const float*)d_in[4];
    const float* x_emb2     = (const float*)d_in[5];
    const float* gcn_W      = (const float*)d_in[6];
    const float* gcn_b      = (const float*)d_in[7];
    const float* ee1        = (const float*)d_in[8];
    const float* ee2        = (const float*)d_in[9];
    const float* bn_g       = (const float*)d_in[10];
    const float* bn_b       = (const float*)d_in[11];
    const float* feat_W     = (const float*)d_in[12];
    const float* feat_b     = (const float*)d_in[13];
    const float* W1         = (const float*)d_in[14];
    const float* b1         = (const float*)d_in[15];
    const float* W2         = (const float*)d_in[16];
    const float* b2         = (const float*)d_in[17];
    const float* W3         = (const float*)d_in[18];
    const float* b3         = (const float*)d_in[19];
    const float* bn1_g      = (const float*)d_in[20];
    const float* bn1_b      = (const float*)d_in[21];
    const float* bn2_g      = (const float*)d_in[22];
    const float* bn2_b      = (const float*)d_in[23];

    const int* e_row = edge_index;        // sources
    const int* e_col = edge_index + EE;   // destinations (segment key)

    // ---- workspace carve-up (256 B aligned) ----
    size_t off = 0;
    auto alloc = [&](size_t bytes) {
        size_t o = off;
        off = (off + bytes + 255) & ~(size_t)255;
        return o;
    };
    char* ws = (char*)d_ws;
    size_t o_bufA   = alloc((size_t)NN * EMB * 4);
    size_t o_bufB   = alloc((size_t)NN * EMB * 4);
    size_t o_degemb = alloc((size_t)LL * NN * 4);
    size_t o_csr    = alloc((size_t)EE * 4);
    size_t o_start  = alloc((size_t)NN * 4);
    // -------- contiguous zero region: deg, cur, gcur, stats --------
    size_t o_deg    = alloc((size_t)NN * 4);
    size_t o_cur    = alloc((size_t)NN * 4);
    size_t o_gcur   = alloc(256);
    size_t o_stats  = alloc((size_t)(5 * 600 + 2 * 512) * 4);
    size_t zero_end = off;
    // ---------------------------------------------------------------
    size_t o_ss     = alloc((size_t)(5 * 600 + 2 * 512) * 4);
    size_t o_he     = alloc((size_t)GG * FEAT * 4);
    size_t o_yb     = alloc((size_t)GG * FEAT * 4);
    if (ws_size < off) return;  // workspace insufficient

    float* bufA   = (float*)(ws + o_bufA);
    float* bufB   = (float*)(ws + o_bufB);
    float* degemb = (float*)(ws + o_degemb);
    int*   csr    = (int*)(ws + o_csr);
    int*   start  = (int*)(ws + o_start);
    int*   deg    = (int*)(ws + o_deg);
    int*   cur    = (int*)(ws + o_cur);
    int*   gcur   = (int*)(ws + o_gcur);
    float* stats  = (float*)(ws + o_stats);
    float* ss     = (float*)(ws + o_ss);
    float* he     = (float*)(ws + o_he);
    float* yb     = (float*)(ws + o_yb);

    float* out_pool = (float*)d_out;                       // [GG, EMB]
    float* out_mlp  = (float*)d_out + (size_t)GG * EMB;    // [GG, FEAT]

    // ---- zero counters/stats in one memset ----
    hipMemsetAsync(ws + o_deg, 0, zero_end - o_deg, stream);

    const int TB = 256;
    int gE  = (EE + TB - 1) / TB;
    int gN  = (NN + TB - 1) / TB;
    int gNE = (NN * EMB4 + TB - 1) / TB;

    // ---- CSR + edge-embedding prep ----
    k_deg<<<gE, TB, 0, stream>>>(e_col, deg);
    k_alloc<<<gN, TB, 0, stream>>>(deg, start, gcur);
    k_fill<<<gE, TB, 0, stream>>>(e_row, e_col, start, cur, csr);

    k_degemb_init<<<(LL * NN + TB - 1) / TB, TB, 0, stream>>>(ee1, ee2, degemb);
    k_degemb_edges<<<gE, TB, 0, stream>>>(e_col, edge_attr, ee1, ee2, degemb);

    // ---- initial node embedding ----
    k_embed<<<gNE, TB, 0, stream>>>(x_nodes, x_emb1, x_emb2, bufA);

    // ---- GCN layers ----
    dim3 gemm_grid((NN + GBM - 1) / GBM, (EMB + GBN - 1) / GBN);
    for (int l = 0; l < LL; ++l) {
        k_agg<<<gNE, TB, 0, stream>>>(bufA, bufB, csr, start, deg);
        k_gemm<<<gemm_grid, TB, 0, stream>>>(bufB, gcn_W + (size_t)l * EMB * EMB, bufA,
                                             NN, EMB, EMB,
                                             degemb + (size_t)l * NN, gcn_b + (size_t)l * EMB);
        float* st = stats + (size_t)l * 600;
        float* sl = ss + (size_t)l * 600;
        k_bn_stats<<<512, TB, 0, stream>>>(bufA, NN, EMB, st);
        k_bn_finalize<<<2, TB, 0, stream>>>(st, bn_g + (size_t)l * EMB, bn_b + (size_t)l * EMB,
                                            1.0f / NN, EMB, sl);
        k_bn_apply<<<gNE, TB, 0, stream>>>(bufA, (long)NN * EMB4, EMB4, sl, EMB, l < LL - 1);
    }

    // ---- pooling (h_pool -> d_out[0 : GG*EMB]) ----
    k_pool<<<GG, TB, 0, stream>>>(bufA, batch, out_pool);

    // ---- MLP head ----
    dim3 g_he((GG + GBM - 1) / GBM, (FEAT + GBN - 1) / GBN);
    k_gemm<<<g_he, TB, 0, stream>>>(out_pool, feat_W, he, GG, FEAT, EMB, nullptr, feat_b);
    k_gemm<<<g_he, TB, 0, stream>>>(he, W1, yb, GG, FEAT, FEAT, nullptr, b1);
    {
        float* st = stats + 5 * 600;
        float* sl = ss + 5 * 600;
        k_bn_stats<<<64, TB, 0, stream>>>(yb, GG, FEAT, st);
        k_bn_finalize<<<1, TB, 0, stream>>>(st, bn1_g, bn1_b, 1.0f / GG, FEAT, sl);
        k_bn_apply<<<(GG * (FEAT / 4) + TB - 1) / TB, TB, 0, stream>>>(
            yb, (long)GG * (FEAT / 4), FEAT / 4, sl, FEAT, 1);
    }
    k_gemm<<<g_he, TB, 0, stream>>>(yb, W2, he, GG, FEAT, FEAT, nullptr, b2);
    {
        float* st = stats + 5 * 600 + 512;
        float* sl = ss + 5 * 600 + 512;
        k_bn_stats<<<64, TB, 0, stream>>>(he, GG, FEAT, st);
        k_bn_finalize<<<1, TB, 0, stream>>>(st, bn2_g, bn2_b, 1.0f / GG, FEAT, sl);
        k_bn_apply<<<(GG * (FEAT / 4) + TB - 1) / TB, TB, 0, stream>>>(
            he, (long)GG * (FEAT / 4), FEAT / 4, sl, FEAT, 1);
    }
    k_gemm<<<g_he, TB, 0, stream>>>(he, W3, out_mlp, GG, FEAT, FEAT, nullptr, b3);
}

// Round 13
// 2677.292 us; speedup vs baseline: 1.7225x; 1.7225x over previous
//
#include <hip/hip_runtime.h>

// Problem constants (match reference setup_inputs()).
constexpr int NN   = 100000;  // nodes
constexpr int EE   = 400000;  // directed edges
constexpr int GG   = 4096;    // graphs
constexpr int EMB  = 300;     // node feature dim
constexpr int FEAT = 256;
constexpr int LL   = 5;
constexpr int EMB4 = EMB / 4;   // 75
constexpr int KP   = 320;       // K padded to multiple of 32
constexpr int NCT  = 19;        // 19 x 16 = 304 >= 300 col tiles
constexpr float EPSV = 1e-5f;

using short8 = __attribute__((ext_vector_type(8))) short;   // 8 bf16 (4 VGPR)
using f32x4  = __attribute__((ext_vector_type(4))) float;   // MFMA acc

__device__ __forceinline__ unsigned short f2bf(float f) {   // RNE float->bf16
    unsigned u = __float_as_uint(f);
    unsigned r = u + 0x7FFFu + ((u >> 16) & 1u);
    return (unsigned short)(r >> 16);
}
__device__ __forceinline__ float bf2f(unsigned short h) {
    return __uint_as_float(((unsigned)h) << 16);
}

// ---------------------------------------------------------------- CSR build
__global__ void k_deg(const int* __restrict__ col, int* __restrict__ deg) {
    int e = blockIdx.x * 256 + threadIdx.x;
    if (e < EE) atomicAdd(&deg[col[e]], 1);
}
__global__ void k_alloc(const int* __restrict__ deg, int* __restrict__ start,
                        int* __restrict__ gcur) {
    int c = blockIdx.x * 256 + threadIdx.x;
    if (c < NN) start[c] = atomicAdd(gcur, deg[c]);
}
__global__ void k_fill(const int* __restrict__ row, const int* __restrict__ col,
                       const int* __restrict__ start, int* __restrict__ cur,
                       int* __restrict__ csr) {
    int e = blockIdx.x * 256 + threadIdx.x;
    if (e >= EE) return;
    int c = col[e];
    int p = start[c] + atomicAdd(&cur[c], 1);
    csr[p] = row[e];
}

// ------------------------------------------------- per-node edge-embedding sum
__global__ void k_degemb_init(const float* __restrict__ ee1, const float* __restrict__ ee2,
                              float* __restrict__ de) {
    int idx = blockIdx.x * 256 + threadIdx.x;
    if (idx >= LL * NN) return;
    int l = idx / NN;
    de[idx] = ee1[l * 5 + 4] + ee2[l * 3 + 0];
}
__global__ void k_degemb_edges(const int* __restrict__ col, const int* __restrict__ ea,
                               const float* __restrict__ ee1, const float* __restrict__ ee2,
                               float* __restrict__ de) {
    int e = blockIdx.x * 256 + threadIdx.x;
    if (e >= EE) return;
    int c  = col[e];
    int t0 = ea[e * 2 + 0];
    int t1 = ea[e * 2 + 1];
#pragma unroll
    for (int l = 0; l < LL; ++l)
        atomicAdd(&de[l * NN + c], ee1[l * 5 + t0] + ee2[l * 3 + t1]);
}

// ---------------------------------------------------------------- node embed
__global__ void k_embed(const int* __restrict__ xn, const float* __restrict__ e1,
                        const float* __restrict__ e2, float* __restrict__ h) {
    int idx = blockIdx.x * 256 + threadIdx.x;
    if (idx >= NN * EMB4) return;
    int node = idx / EMB4;
    int c    = idx % EMB4;
    int a0 = xn[node * 2 + 0];
    int a1 = xn[node * 2 + 1];
    const float4* e1_4 = (const float4*)e1;
    const float4* e2_4 = (const float4*)e2;
    float4 u = e1_4[(size_t)a0 * EMB4 + c];
    float4 v = e2_4[(size_t)a1 * EMB4 + c];
    ((float4*)h)[idx] = make_float4(u.x + v.x, u.y + v.y, u.z + v.z, u.w + v.w);
}

// ------------------------------------------- W -> staging-linear bf16 hi/lo
// per layer: [10 kc][2 hl][19 ct][4 g][16 c0][8 j]; k = kc*32+g*8+j, n = ct*16+c0
__global__ void k_wconv(const float* __restrict__ W, unsigned short* __restrict__ bswz) {
    int idx = blockIdx.x * 256 + threadIdx.x;
    if (idx >= LL * 10 * 19456) return;
    int l   = idx / 194560;
    int rem = idx % 194560;
    int kc  = rem / 19456; rem %= 19456;
    int hl  = rem / 9728;  rem %= 9728;
    int ct  = rem / 512;   rem %= 512;
    int gg  = rem / 128;   rem %= 128;
    int c0  = rem / 8;
    int j   = rem % 8;
    int k = kc * 32 + gg * 8 + j;
    int n = ct * 16 + c0;
    float v = (k < EMB && n < EMB) ? W[(size_t)l * EMB * EMB + (size_t)k * EMB + n] : 0.f;
    unsigned short hi = f2bf(v);
    unsigned short outv = hi;
    if (hl) outv = f2bf(v - bf2f(hi));
    bswz[idx] = outv;
}

// --------------------------------------- fused BN-apply + ReLU + aggregation
// reads y (pre-BN activations of previous layer, or raw embed when ss==null),
// reconstructs h = relu(y*sc+sh), aggregates self + CSR neighbors, and emits
// the split-bf16 operand arrays ahi/alo in [NN][KP] layout (zero k-pad).
__global__ void k_agg_fused(const float* __restrict__ y, const float* __restrict__ ss,
                            int relu,
                            const int* __restrict__ csr, const int* __restrict__ start,
                            const int* __restrict__ deg,
                            unsigned short* __restrict__ ahi, unsigned short* __restrict__ alo) {
    int idx = blockIdx.x * 256 + threadIdx.x;
    if (idx >= NN * 80) return;               // 80 float4 groups = KP/4
    int node = idx / 80;
    int c4   = idx % 80;
    size_t ob = (size_t)node * KP + c4 * 4;
    if (c4 >= EMB4) {                          // zero k-pad (300..319)
        ushort4 z = make_ushort4(0, 0, 0, 0);
        *(ushort4*)&ahi[ob] = z;
        *(ushort4*)&alo[ob] = z;
        return;
    }
    float4 sc = make_float4(1.f, 1.f, 1.f, 1.f);
    float4 sh = make_float4(0.f, 0.f, 0.f, 0.f);
    if (ss) {
        sc = *(const float4*)&ss[c4 * 4];
        sh = *(const float4*)&ss[EMB + c4 * 4];
    }
    const float4* y4 = (const float4*)y;
    float4 a = y4[(size_t)node * EMB4 + c4];
    a.x = a.x * sc.x + sh.x; a.y = a.y * sc.y + sh.y;
    a.z = a.z * sc.z + sh.z; a.w = a.w * sc.w + sh.w;
    if (relu) {
        a.x = fmaxf(a.x, 0.f); a.y = fmaxf(a.y, 0.f);
        a.z = fmaxf(a.z, 0.f); a.w = fmaxf(a.w, 0.f);
    }
    int s = start[node];
    int d = deg[node];
    for (int i = 0; i < d; ++i) {
        float4 v = y4[(size_t)csr[s + i] * EMB4 + c4];
        v.x = v.x * sc.x + sh.x; v.y = v.y * sc.y + sh.y;
        v.z = v.z * sc.z + sh.z; v.w = v.w * sc.w + sh.w;
        if (relu) {
            v.x = fmaxf(v.x, 0.f); v.y = fmaxf(v.y, 0.f);
            v.z = fmaxf(v.z, 0.f); v.w = fmaxf(v.w, 0.f);
        }
        a.x += v.x; a.y += v.y; a.z += v.z; a.w += v.w;
    }
    ushort4 hi, lo;
    hi.x = f2bf(a.x); lo.x = f2bf(a.x - bf2f(hi.x));
    hi.y = f2bf(a.y); lo.y = f2bf(a.y - bf2f(hi.y));
    hi.z = f2bf(a.z); lo.z = f2bf(a.z - bf2f(hi.z));
    hi.w = f2bf(a.w); lo.w = f2bf(a.w - bf2f(hi.w));
    *(ushort4*)&ahi[ob] = hi;
    *(ushort4*)&alo[ob] = lo;
}

// ------------------------------------------- split-bf16 MFMA GEMM (node path)
// y[NN][300] = A[NN][300] @ W[300][300] + degemb[r] + bias[c]
// A given as bf16 hi/lo in [NN][KP]; W pre-swizzled per layer (k_wconv layout).
// Block: 128 rows x full N (19 col frags), BK=32, 256 threads = 4 waves.
// C = ah*bh + al*bh + ah*bl  (al*bl dropped, ~2^-16 relative).
__global__ __launch_bounds__(256) void k_gemm_mfma(
    const unsigned short* __restrict__ ahi, const unsigned short* __restrict__ alo,
    const unsigned short* __restrict__ bswz,   // this layer: [10][2*9728]
    float* __restrict__ y,
    const float* __restrict__ row_add, const float* __restrict__ col_bias) {
    __shared__ unsigned short lA[8192];    // [2 hl][8 rt][4 g][16 r0][8 j]
    __shared__ unsigned short lB[19456];   // [2 hl][19 ct][4 g][16 c0][8 j]
    const int tid  = threadIdx.x;
    const int w    = tid >> 6;
    const int lane = tid & 63;
    const int g    = lane >> 4;
    const int rc0  = lane & 15;
    const int bm0  = blockIdx.x * 128;

    f32x4 acc[2][NCT];
    f32x4 zz = {0.f, 0.f, 0.f, 0.f};
#pragma unroll
    for (int rt = 0; rt < 2; ++rt)
#pragma unroll
        for (int ct = 0; ct < NCT; ++ct) acc[rt][ct] = zz;

    for (int kc = 0; kc < 10; ++kc) {
        __syncthreads();
        // stage A: 1024 fragment copies (16B each), 4 per thread
#pragma unroll
        for (int it = 0; it < 4; ++it) {
            int idx = it * 256 + tid;
            int hl = idx >> 9;
            int rm = (idx >> 2) & 127;
            int gg = idx & 3;
            const unsigned short* src =
                (hl ? alo : ahi) + (size_t)(bm0 + rm) * KP + kc * 32 + gg * 8;
            float4 v = *(const float4*)src;
            *(float4*)&lA[hl * 4096 + (((rm >> 4) * 4 + gg) * 16 + (rm & 15)) * 8] = v;
        }
        // stage B: straight 16B copy of the pre-swizzled chunk
        const unsigned short* bs = bswz + (size_t)kc * 19456;
        for (int i = tid; i < 2432; i += 256)
            *(float4*)&lB[i * 8] = *(const float4*)&bs[i * 8];
        __syncthreads();

        short8 ah[2], al[2];
#pragma unroll
        for (int rt = 0; rt < 2; ++rt) {
            int off = (((w * 2 + rt) * 4 + g) * 16 + rc0) * 8;
            ah[rt] = *(const short8*)&lA[off];
            al[rt] = *(const short8*)&lA[4096 + off];
        }
#pragma unroll
        for (int ct = 0; ct < NCT; ++ct) {
            int boff = ((ct * 4 + g) * 16 + rc0) * 8;
            short8 bh = *(const short8*)&lB[boff];
            short8 bl = *(const short8*)&lB[9728 + boff];
#pragma unroll
            for (int rt = 0; rt < 2; ++rt) {
                acc[rt][ct] = __builtin_amdgcn_mfma_f32_16x16x32_bf16(ah[rt], bh, acc[rt][ct], 0, 0, 0);
                acc[rt][ct] = __builtin_amdgcn_mfma_f32_16x16x32_bf16(al[rt], bh, acc[rt][ct], 0, 0, 0);
                acc[rt][ct] = __builtin_amdgcn_mfma_f32_16x16x32_bf16(ah[rt], bl, acc[rt][ct], 0, 0, 0);
            }
        }
    }
    // epilogue: C row = g*4+q, col = ct*16+rc0 (HW-verified C/D layout)
#pragma unroll
    for (int rt = 0; rt < 2; ++rt) {
#pragma unroll
        for (int q = 0; q < 4; ++q) {
            int r = bm0 + (w * 2 + rt) * 16 + g * 4 + q;
            if (r >= NN) continue;
            float ra = row_add[r];
#pragma unroll
            for (int ct = 0; ct < NCT; ++ct) {
                int c = ct * 16 + rc0;
                if (c < EMB)
                    y[(size_t)r * EMB + c] = acc[rt][ct][q] + ra + col_bias[c];
            }
        }
    }
}

// ---------------------------------------------------------------- fp32 GEMM (MLP head)
#define GBM 128
#define GBN 64
#define GBK 16
__global__ __launch_bounds__(256) void k_gemm(
    const float* __restrict__ A, const float* __restrict__ B, float* __restrict__ C,
    int M, int N, int K,
    const float* __restrict__ row_add, const float* __restrict__ col_bias) {
    __shared__ float As[GBK][GBM + 4];
    __shared__ float Bs[GBK][GBN + 4];
    const int t  = threadIdx.x;
    const int tx = t & 15;
    const int ty = t >> 4;
    const int bm0 = blockIdx.x * GBM;
    const int bn0 = blockIdx.y * GBN;
    float acc[8][4];
#pragma unroll
    for (int i = 0; i < 8; ++i)
#pragma unroll
        for (int j = 0; j < 4; ++j) acc[i][j] = 0.f;
    for (int k0 = 0; k0 < K; k0 += GBK) {
#pragma unroll
        for (int i = 0; i < 8; ++i) {
            int id = t + i * 256;
            int kk = id & 15, m = id >> 4;
            int r = bm0 + m, k = k0 + kk;
            As[kk][m] = (r < M && k < K) ? A[(size_t)r * K + k] : 0.f;
        }
#pragma unroll
        for (int i = 0; i < 4; ++i) {
            int id = t + i * 256;
            int n = id & 63, kk = id >> 6;
            int k = k0 + kk, c = bn0 + n;
            Bs[kk][n] = (k < K && c < N) ? B[(size_t)k * N + c] : 0.f;
        }
        __syncthreads();
#pragma unroll
        for (int kk = 0; kk < GBK; ++kk) {
            float4 a0 = *(const float4*)&As[kk][ty * 8];
            float4 a1 = *(const float4*)&As[kk][ty * 8 + 4];
            float4 b  = *(const float4*)&Bs[kk][tx * 4];
            float av[8] = {a0.x, a0.y, a0.z, a0.w, a1.x, a1.y, a1.z, a1.w};
            float bv[4] = {b.x, b.y, b.z, b.w};
#pragma unroll
            for (int i = 0; i < 8; ++i)
#pragma unroll
                for (int j = 0; j < 4; ++j) acc[i][j] += av[i] * bv[j];
        }
        __syncthreads();
    }
#pragma unroll
    for (int i = 0; i < 8; ++i) {
        int r = bm0 + ty * 8 + i;
        if (r >= M) continue;
        float ra = row_add ? row_add[r] : 0.f;
#pragma unroll
        for (int j = 0; j < 4; ++j) {
            int c = bn0 + tx * 4 + j;
            if (c >= N) continue;
            float v = acc[i][j] + ra;
            if (col_bias) v += col_bias[c];
            C[(size_t)r * N + c] = v;
        }
    }
}

// ---------------------------------------------------------------- BatchNorm
__global__ void k_bn_stats(const float* __restrict__ x, int nrows, int fdim,
                           float* __restrict__ sums) {
    int t = threadIdx.x;  // 256
    int rows_per = (nrows + gridDim.x - 1) / gridDim.x;
    int r0 = blockIdx.x * rows_per;
    int r1 = min(nrows, r0 + rows_per);
    bool has2 = (t + 256) < fdim;
    float s0 = 0.f, q0 = 0.f, s1 = 0.f, q1 = 0.f;
    for (int r = r0; r < r1; ++r) {
        const float* row = x + (size_t)r * fdim;
        float v = row[t];
        s0 += v; q0 += v * v;
        if (has2) { float w2 = row[t + 256]; s1 += w2; q1 += w2 * w2; }
    }
    atomicAdd(&sums[t], s0);
    atomicAdd(&sums[fdim + t], q0);
    if (has2) {
        atomicAdd(&sums[t + 256], s1);
        atomicAdd(&sums[fdim + t + 256], q1);
    }
}
__global__ void k_bn_finalize(const float* __restrict__ sums, const float* __restrict__ gamma,
                              const float* __restrict__ beta, float inv_n, int fdim,
                              float* __restrict__ ss) {
    int f = blockIdx.x * 256 + threadIdx.x;
    if (f >= fdim) return;
    float mean = sums[f] * inv_n;
    float var  = sums[fdim + f] * inv_n - mean * mean;
    float sc   = gamma[f] * rsqrtf(var + EPSV);
    ss[f] = sc;
    ss[fdim + f] = beta[f] - mean * sc;
}
__global__ void k_bn_apply(float* __restrict__ x, long total4, int f4dim,
                           const float* __restrict__ ss, int fdim, int relu) {
    long idx = (long)blockIdx.x * 256 + threadIdx.x;
    if (idx >= total4) return;
    int c4 = (int)(idx % f4dim);
    float4 v = ((float4*)x)[idx];
    float4 sc = *(const float4*)&ss[c4 * 4];
    float4 sh = *(const float4*)&ss[fdim + c4 * 4];
    v.x = v.x * sc.x + sh.x;
    v.y = v.y * sc.y + sh.y;
    v.z = v.z * sc.z + sh.z;
    v.w = v.w * sc.w + sh.w;
    if (relu) {
        v.x = fmaxf(v.x, 0.f); v.y = fmaxf(v.y, 0.f);
        v.z = fmaxf(v.z, 0.f); v.w = fmaxf(v.w, 0.f);
    }
    ((float4*)x)[idx] = v;
}

// ------------------------------------------- mean pool (+ final BN transform)
// mean(bn(y)) == bn(mean(y)) since BN is a per-column affine map (exact).
__global__ void k_pool(const float* __restrict__ y, const int* __restrict__ batch,
                       const float* __restrict__ ss, float* __restrict__ out) {
    int g = blockIdx.x;
    int t = threadIdx.x;  // 256
    int lo = 0, hi = NN;
    while (lo < hi) { int m = (lo + hi) >> 1; if (batch[m] < g) lo = m + 1; else hi = m; }
    int s = lo;
    int g1 = g + 1;
    lo = 0; hi = NN;
    while (lo < hi) { int m = (lo + hi) >> 1; if (batch[m] < g1) lo = m + 1; else hi = m; }
    int e = lo;
    float a0 = 0.f, a1 = 0.f;
    for (int r = s; r < e; ++r) {
        const float* row = y + (size_t)r * EMB;
        a0 += row[t];
        if (t < EMB - 256) a1 += row[t + 256];
    }
    int cnt = e - s;
    float inv = (cnt > 0) ? 1.0f / (float)cnt : 0.f;
    out[(size_t)g * EMB + t] = (cnt > 0) ? (a0 * inv) * ss[t] + ss[EMB + t] : 0.f;
    if (t < EMB - 256) {
        int c = t + 256;
        out[(size_t)g * EMB + c] = (cnt > 0) ? (a1 * inv) * ss[c] + ss[EMB + c] : 0.f;
    }
}

// ---------------------------------------------------------------- launcher
extern "C" void kernel_launch(void* const* d_in, const int* in_sizes, int n_in,
                              void* d_out, int out_size, void* d_ws, size_t ws_size,
                              hipStream_t stream) {
    const int*   x_nodes    = (const int*)d_in[0];
    const int*   edge_index = (const int*)d_in[1];
    const int*   edge_attr  = (const int*)d_in[2];
    const int*   batch      = (const int*)d_in[3];
    const float* x_emb1     = (const float*)d_in[4];
    const float* x_emb2     = (const float*)d_in[5];
    const float* gcn_W      = (const float*)d_in[6];
    const float* gcn_b      = (const float*)d_in[7];
    const float* ee1        = (const float*)d_in[8];
    const float* ee2        = (const float*)d_in[9];
    const float* bn_g       = (const float*)d_in[10];
    const float* bn_b       = (const float*)d_in[11];
    const float* feat_W     = (const float*)d_in[12];
    const float* feat_b     = (const float*)d_in[13];
    const float* W1         = (const float*)d_in[14];
    const float* b1         = (const float*)d_in[15];
    const float* W2         = (const float*)d_in[16];
    const float* b2         = (const float*)d_in[17];
    const float* W3         = (const float*)d_in[18];
    const float* b3         = (const float*)d_in[19];
    const float* bn1_g      = (const float*)d_in[20];
    const float* bn1_b      = (const float*)d_in[21];
    const float* bn2_g      = (const float*)d_in[22];
    const float* bn2_b      = (const float*)d_in[23];

    const int* e_row = edge_index;        // sources
    const int* e_col = edge_index + EE;   // destinations (segment key)

    size_t off = 0;
    auto alloc = [&](size_t bytes) {
        size_t o = off;
        off = (off + bytes + 255) & ~(size_t)255;
        return o;
    };
    char* ws = (char*)d_ws;
    size_t o_y      = alloc((size_t)NN * EMB * 4);            // fp32 activations (also embed)
    size_t o_ahi    = alloc((size_t)(NN + 96) * KP * 2);      // bf16 hi (row pad for tile overrun)
    size_t o_alo    = alloc((size_t)(NN + 96) * KP * 2);      // bf16 lo
    size_t o_bswz   = alloc((size_t)LL * 194560 * 2);         // pre-swizzled W
    size_t o_degemb = alloc((size_t)LL * NN * 4);
    size_t o_csr    = alloc((size_t)EE * 4);
    size_t o_start  = alloc((size_t)NN * 4);
    // -------- contiguous zero region: deg, cur, gcur, stats --------
    size_t o_deg    = alloc((size_t)NN * 4);
    size_t o_cur    = alloc((size_t)NN * 4);
    size_t o_gcur   = alloc(256);
    size_t o_stats  = alloc((size_t)(5 * 600 + 2 * 512) * 4);
    size_t zero_end = off;
    // ---------------------------------------------------------------
    size_t o_ss     = alloc((size_t)(5 * 600 + 2 * 512) * 4);
    if (ws_size < off) return;  // workspace insufficient

    float*          y      = (float*)(ws + o_y);
    unsigned short* ahi    = (unsigned short*)(ws + o_ahi);
    unsigned short* alo    = (unsigned short*)(ws + o_alo);
    unsigned short* bswz   = (unsigned short*)(ws + o_bswz);
    float*          degemb = (float*)(ws + o_degemb);
    int*            csr    = (int*)(ws + o_csr);
    int*            start  = (int*)(ws + o_start);
    int*            deg    = (int*)(ws + o_deg);
    int*            cur    = (int*)(ws + o_cur);
    int*            gcur   = (int*)(ws + o_gcur);
    float*          stats  = (float*)(ws + o_stats);
    float*          ss     = (float*)(ws + o_ss);
    // he/yb (4096x256 fp32, 4MB each) alias the ahi region: ahi is dead after
    // the last node GEMM, and every replay rewrites ahi (k_agg_fused) first.
    float* he = (float*)(ws + o_ahi);
    float* yb = (float*)(ws + o_ahi + (size_t)GG * FEAT * 4);

    float* out_pool = (float*)d_out;                       // [GG, EMB]
    float* out_mlp  = (float*)d_out + (size_t)GG * EMB;    // [GG, FEAT]

    hipMemsetAsync(ws + o_deg, 0, zero_end - o_deg, stream);

    const int TB = 256;
    int gE  = (EE + TB - 1) / TB;
    int gN  = (NN + TB - 1) / TB;
    int gNE = (NN * EMB4 + TB - 1) / TB;
    int gAG = (NN * 80 + TB - 1) / TB;

    // ---- CSR + edge-embedding prep ----
    k_deg<<<gE, TB, 0, stream>>>(e_col, deg);
    k_alloc<<<gN, TB, 0, stream>>>(deg, start, gcur);
    k_fill<<<gE, TB, 0, stream>>>(e_row, e_col, start, cur, csr);
    k_degemb_init<<<(LL * NN + TB - 1) / TB, TB, 0, stream>>>(ee1, ee2, degemb);
    k_degemb_edges<<<gE, TB, 0, stream>>>(e_col, edge_attr, ee1, ee2, degemb);

    // ---- weight pre-swizzle (bf16 hi/lo) ----
    k_wconv<<<(LL * 10 * 19456 + TB - 1) / TB, TB, 0, stream>>>(gcn_W, bswz);

    // ---- initial node embedding (fp32, into y) ----
    k_embed<<<gNE, TB, 0, stream>>>(x_nodes, x_emb1, x_emb2, y);

    // ---- GCN layers ----
    const int gemm_grid = (NN + 127) / 128;   // 782 blocks, full N per block
    for (int l = 0; l < LL; ++l) {
        const float* ssl = (l == 0) ? nullptr : (ss + (size_t)(l - 1) * 600);
        k_agg_fused<<<gAG, TB, 0, stream>>>(y, ssl, (l > 0) ? 1 : 0,
                                            csr, start, deg, ahi, alo);
        k_gemm_mfma<<<gemm_grid, TB, 0, stream>>>(ahi, alo,
                                                  bswz + (size_t)l * 194560, y,
                                                  degemb + (size_t)l * NN,
                                                  gcn_b + (size_t)l * EMB);
        float* st = stats + (size_t)l * 600;
        float* sl = ss + (size_t)l * 600;
        k_bn_stats<<<512, TB, 0, stream>>>(y, NN, EMB, st);
        k_bn_finalize<<<2, TB, 0, stream>>>(st, bn_g + (size_t)l * EMB, bn_b + (size_t)l * EMB,
                                            1.0f / NN, EMB, sl);
    }

    // ---- pooling with final BN transform (h_pool -> d_out[0 : GG*EMB]) ----
    k_pool<<<GG, TB, 0, stream>>>(y, batch, ss + (size_t)(LL - 1) * 600, out_pool);

    // ---- MLP head (fp32 path; small) ----
    dim3 g_he((GG + GBM - 1) / GBM, (FEAT + GBN - 1) / GBN);
    k_gemm<<<g_he, TB, 0, stream>>>(out_pool, feat_W, he, GG, FEAT, EMB, nullptr, feat_b);
    k_gemm<<<g_he, TB, 0, stream>>>(he, W1, yb, GG, FEAT, FEAT, nullptr, b1);
    {
        float* st = stats + 5 * 600;
        float* sl = ss + 5 * 600;
        k_bn_stats<<<64, TB, 0, stream>>>(yb, GG, FEAT, st);
        k_bn_finalize<<<1, TB, 0, stream>>>(st, bn1_g, bn1_b, 1.0f / GG, FEAT, sl);
        k_bn_apply<<<(GG * (FEAT / 4) + TB - 1) / TB, TB, 0, stream>>>(
            yb, (long)GG * (FEAT / 4), FEAT / 4, sl, FEAT, 1);
    }
    k_gemm<<<g_he, TB, 0, stream>>>(yb, W2, he, GG, FEAT, FEAT, nullptr, b2);
    {
        float* st = stats + 5 * 600 + 512;
        float* sl = ss + 5 * 600 + 512;
        k_bn_stats<<<64, TB, 0, stream>>>(he, GG, FEAT, st);
        k_bn_finalize<<<1, TB, 0, stream>>>(st, bn2_g, bn2_b, 1.0f / GG, FEAT, sl);
        k_bn_apply<<<(GG * (FEAT / 4) + TB - 1) / TB, TB, 0, stream>>>(
            he, (long)GG * (FEAT / 4), FEAT / 4, sl, FEAT, 1);
    }
    k_gemm<<<g_he, TB, 0, stream>>>(he, W3, out_mlp, GG, FEAT, FEAT, nullptr, b3);
}